// Round 7
// baseline (369.893 us; speedup 1.0000x reference)
//
#include <hip/hip_runtime.h>

#define BATCH_L 524288
#define NL 40
#define NXL 20
#define BLOCK 256
#define GRID 2048
#define NTHREADS (GRID * BLOCK)                    // 524288
#define NHALF (BATCH_L * 2)                        // 1048576 half-rows

// Native clang vector type — __builtin_nontemporal_load requires it.
typedef float vfloat4 __attribute__((ext_vector_type(4)));

// Process one half-row (20 floats) held in registers. Stencil boundary values
// come from the partner lane (t^1) via __shfl_xor.
__device__ __forceinline__ void half_row(const vfloat4 pc[5], const vfloat4 tc[5],
                                         const vfloat4 yc[5], float ddmask,
                                         float& sdd, float& spi)
{
    float p[20];
#pragma unroll
    for (int k = 0; k < 5; ++k) {
        p[4 * k + 0] = pc[k].x; p[4 * k + 1] = pc[k].y;
        p[4 * k + 2] = pc[k].z; p[4 * k + 3] = pc[k].w;
    }

    float s = 0.f;
#pragma unroll
    for (int k = 0; k < 5; ++k) {
        const float d0 = pc[k].x - tc[k].x;
        const float d1 = pc[k].y - tc[k].y;
        const float d2 = pc[k].z - tc[k].z;
        const float d3 = pc[k].w - tc[k].w;
        s += d0 * d0 + d1 * d1 + d2 * d2 + d3 * d3;
    }
    sdd += ddmask * s;

    const float prev2 = __shfl_xor(p[18], 1);
    const float prev1 = __shfl_xor(p[19], 1);
    const float nxt   = __shfl_xor(p[0], 1);

    const float* y = reinterpret_cast<const float*>(yc);
    float d = (101.f * p[0] - 100.f * y[0] - 8.f) - (p[1] - prev2) * prev1;
    spi += d * d;
    d = (101.f * p[1] - 100.f * y[1] - 8.f) - (p[2] - prev1) * p[0];
    spi += d * d;
#pragma unroll
    for (int i = 2; i <= 18; ++i) {
        d = (101.f * p[i] - 100.f * y[i] - 8.f) - (p[i + 1] - p[i - 2]) * p[i - 1];
        spi += d * d;
    }
    d = (101.f * p[19] - 100.f * y[19] - 8.f) - (nxt - p[17]) * p[18];
    spi += d * d;
}

// All 30 nontemporal dwordx4 loads are issued UP FRONT (both half-rows) so each
// wave exposes its full line budget to the CU's miss queue before any waitcnt —
// max MSHR duty cycle. Finalize is folded in via the last-block-done pattern.
__global__ void hybrid_loss_main(
    const vfloat4* __restrict__ pred4,
    const vfloat4* __restrict__ targ4,
    const vfloat4* __restrict__ ycur4,
    double* __restrict__ sums,          // ws: [0]=sum_dd, [1]=sum_pi
    unsigned int* __restrict__ counter, // ws: block-completion ticket
    float* __restrict__ out)
{
    const int t = blockIdx.x * BLOCK + threadIdx.x;
    const float ddmask = (threadIdx.x & 1) ? 0.f : 1.f;  // h==0 half has the dd term

    const size_t c0 = 5 * (size_t)t;                     // half-row 0 chunks
    const size_t c1 = 5 * ((size_t)t + NTHREADS);        // half-row 1 chunks

    vfloat4 pc0[5], tc0[5], yc0[5], pc1[5], tc1[5], yc1[5];
#pragma unroll
    for (int k = 0; k < 5; ++k) pc0[k] = __builtin_nontemporal_load(&pred4[c0 + k]);
#pragma unroll
    for (int k = 0; k < 5; ++k) tc0[k] = __builtin_nontemporal_load(&targ4[c0 + k]);
#pragma unroll
    for (int k = 0; k < 5; ++k) yc0[k] = __builtin_nontemporal_load(&ycur4[c0 + k]);
#pragma unroll
    for (int k = 0; k < 5; ++k) pc1[k] = __builtin_nontemporal_load(&pred4[c1 + k]);
#pragma unroll
    for (int k = 0; k < 5; ++k) tc1[k] = __builtin_nontemporal_load(&targ4[c1 + k]);
#pragma unroll
    for (int k = 0; k < 5; ++k) yc1[k] = __builtin_nontemporal_load(&ycur4[c1 + k]);

    float sdd = 0.f, spi = 0.f;
    half_row(pc0, tc0, yc0, ddmask, sdd, spi);
    half_row(pc1, tc1, yc1, ddmask, sdd, spi);

    // Wave shuffle reduction in double -> LDS -> block total.
    double sd = (double)sdd, sp = (double)spi;
#pragma unroll
    for (int off = 32; off > 0; off >>= 1) {
        sd += __shfl_down(sd, off, 64);
        sp += __shfl_down(sp, off, 64);
    }
    __shared__ double lds_red[2 * (BLOCK / 64)];
    const int lane = threadIdx.x & 63;
    const int wave = threadIdx.x >> 6;
    if (lane == 0) { lds_red[2 * wave] = sd; lds_red[2 * wave + 1] = sp; }
    __syncthreads();
    if (threadIdx.x == 0) {
        double tsd = 0.0, tsp = 0.0;
#pragma unroll
        for (int w = 0; w < BLOCK / 64; ++w) {
            tsd += lds_red[2 * w];
            tsp += lds_red[2 * w + 1];
        }
        atomicAdd(&sums[0], tsd);          // device-scope by default
        atomicAdd(&sums[1], tsp);
        __threadfence();
        const unsigned int ticket = atomicAdd(counter, 1u);
        if (ticket == GRID - 1) {          // last block finalizes
            const double v0 = atomicAdd(&sums[0], 0.0);  // atomic read, coherent
            const double v1 = atomicAdd(&sums[1], 0.0);
            const double l_dd = v0 / ((double)BATCH_L * NXL);
            const double l_pi = v1 / ((double)BATCH_L * NL);
            out[0] = (float)(l_dd + 0.1 * l_pi);
            out[1] = (float)l_dd;
            out[2] = (float)l_pi;
        }
    }
}

extern "C" void kernel_launch(void* const* d_in, const int* in_sizes, int n_in,
                              void* d_out, int out_size, void* d_ws, size_t ws_size,
                              hipStream_t stream) {
    const vfloat4* pred = (const vfloat4*)d_in[0];
    const vfloat4* targ = (const vfloat4*)d_in[1];
    const vfloat4* ycur = (const vfloat4*)d_in[2];
    double* sums = (double*)d_ws;                        // 2 doubles
    unsigned int* counter = (unsigned int*)((char*)d_ws + 16);
    float* out = (float*)d_out;

    // ws is poisoned with 0xAA before every timed launch — zero accumulators+ticket.
    hipMemsetAsync(d_ws, 0, 24, stream);
    hybrid_loss_main<<<GRID, BLOCK, 0, stream>>>(pred, targ, ycur, sums, counter, out);
}